// Round 10
// baseline (139.545 us; speedup 1.0000x reference)
//
#include <hip/hip_runtime.h>

typedef __attribute__((ext_vector_type(4))) short short4v;
typedef __attribute__((ext_vector_type(8))) short short8v;
typedef __attribute__((ext_vector_type(4))) float float4v;
typedef __attribute__((ext_vector_type(4))) int int4v;

#define GLD_LDS16(gsrc, ldst)                                                             \
    __builtin_amdgcn_global_load_lds(                                                     \
        (const __attribute__((address_space(1))) void*)(gsrc),                            \
        (__attribute__((address_space(3))) void*)(ldst), 16, 0, 0)

__device__ __forceinline__ short f2bf(float f) {
    unsigned u = __builtin_bit_cast(unsigned, f);
    u += 0x7fffu + ((u >> 16) & 1u);
    return (short)(u >> 16);
}

// ---------------- x: fp32 -> bf16 (vectorized) ----------------
__global__ void k_cvt_x(const float* __restrict__ x, short* __restrict__ xb) {
    int i = blockIdx.x * blockDim.x + threadIdx.x;
    float4v v = ((const float4v*)x)[i];
    short4v o;
    o[0] = f2bf(v[0]); o[1] = f2bf(v[1]); o[2] = f2bf(v[2]); o[3] = f2bf(v[3]);
    ((short4v*)xb)[i] = o;
}

// ---------------- W[k][n] fp32 -> Wt[n][k] bf16 (LDS tile transpose) ----------------
__global__ void k_transpose(const float* __restrict__ W0, const float* __restrict__ W1,
                            const float* __restrict__ W2, const float* __restrict__ W3,
                            short* __restrict__ Wt) {
    const float* W = blockIdx.z == 0 ? W0 : blockIdx.z == 1 ? W1 : blockIdx.z == 2 ? W2 : W3;
    short* dst = Wt + (size_t)blockIdx.z * 1024 * 1024;
    __shared__ float tile[32][33];
    int x0 = blockIdx.x * 32, y0 = blockIdx.y * 32;
    int tx = threadIdx.x, ty = threadIdx.y;
#pragma unroll
    for (int j = 0; j < 4; j++) {
        int r = ty + j * 8;
        tile[r][tx] = W[(size_t)(y0 + r) * 1024 + x0 + tx];
    }
    __syncthreads();
#pragma unroll
    for (int j = 0; j < 4; j++) {
        int r = ty + j * 8;
        dst[(size_t)(x0 + r) * 1024 + y0 + tx] = f2bf(tile[tx][r]);
    }
}

// ---------------- bf16 MFMA GEMM v2: 128x128 tile, BK=64, 8 waves, 2-phase dbuf ------
template <int MODE>
__launch_bounds__(512, 4)
__global__ void k_gemm2(const short* __restrict__ A, const short* __restrict__ Bt,
                        short* __restrict__ out0, short* __restrict__ out1,
                        float* __restrict__ outF) {
    __shared__ short As[2][128][64];
    __shared__ short Bs[2][128][64];
    int t = threadIdx.x;
    int l = t & 63, w = t >> 6;
    int wm = w >> 2, wn = w & 3;
    int lr = l & 15, lg = l >> 4;
    int m0 = blockIdx.x * 128, n0 = blockIdx.y * 128;
    const short* Bp = Bt + (MODE == 0 ? ((size_t)blockIdx.z << 20) : 0);

    int srow = l >> 3;
    int sg = (l & 7) ^ srow;
    const short* Ab0 = A + (size_t)(m0 + w * 8 + srow) * 1024 + sg * 8;
    const short* Ab1 = Ab0 + 64 * 1024;
    const short* Bb0 = Bp + (size_t)(n0 + w * 8 + srow) * 1024 + sg * 8;
    const short* Bb1 = Bb0 + 64 * 1024;

    float4v acc[4][2] = {};

#define STAGE(bb, k0)                                   \
    do {                                                \
        GLD_LDS16(Ab0 + (k0), &As[bb][w * 8][0]);       \
        GLD_LDS16(Ab1 + (k0), &As[bb][64 + w * 8][0]);  \
        GLD_LDS16(Bb0 + (k0), &Bs[bb][w * 8][0]);       \
        GLD_LDS16(Bb1 + (k0), &Bs[bb][64 + w * 8][0]);  \
    } while (0)

    STAGE(0, 0);
    __syncthreads();
    int cur = 0;

    for (int kt = 0; kt < 16; kt++) {
        if (kt + 1 < 16) STAGE(cur ^ 1, (kt + 1) * 64);
#pragma unroll
        for (int ks = 0; ks < 2; ks++) {
            short8v af[4], bfv[2];
            int hh = ks * 4 + lg;
            int sw = ((hh ^ (lr & 7)) * 8);
#pragma unroll
            for (int fm = 0; fm < 4; fm++)
                af[fm] = *(const short8v*)&As[cur][wm * 64 + fm * 16 + lr][sw];
#pragma unroll
            for (int fn = 0; fn < 2; fn++)
                bfv[fn] = *(const short8v*)&Bs[cur][wn * 32 + fn * 16 + lr][sw];
            __builtin_amdgcn_s_setprio(1);
#pragma unroll
            for (int fm = 0; fm < 4; fm++)
#pragma unroll
                for (int fn = 0; fn < 2; fn++)
                    acc[fm][fn] = (MODE == 1)
                        ? __builtin_amdgcn_mfma_f32_16x16x32_bf16(bfv[fn], af[fm], acc[fm][fn], 0, 0, 0)
                        : __builtin_amdgcn_mfma_f32_16x16x32_bf16(af[fm], bfv[fn], acc[fm][fn], 0, 0, 0);
            __builtin_amdgcn_s_setprio(0);
        }
        __syncthreads();
        cur ^= 1;
    }
#undef STAGE

    if (MODE == 0) {
        short* out = (blockIdx.z == 0) ? out0 : out1;
        float scale = (blockIdx.z == 0) ? 0.125f * 1.44269504088896f : 1.0f;
#pragma unroll
        for (int fm = 0; fm < 4; fm++)
#pragma unroll
            for (int fn = 0; fn < 2; fn++)
#pragma unroll
                for (int r = 0; r < 4; r++) {
                    int m = m0 + wm * 64 + fm * 16 + lg * 4 + r;
                    int n = n0 + wn * 32 + fn * 16 + lr;
                    float v = acc[fm][fn][r] * scale;
                    int b = m >> 11, s = m & 2047, h = n >> 6, dh = n & 63;
                    out[(((size_t)(b * 16 + h)) * 2048 + s) * 64 + dh] = f2bf(v);
                }
    } else if (MODE == 1) {
#pragma unroll
        for (int fm = 0; fm < 4; fm++)
#pragma unroll
            for (int fn = 0; fn < 2; fn++)
#pragma unroll
                for (int r = 0; r < 4; r++) {
                    int n = n0 + wn * 32 + fn * 16 + lg * 4 + r;
                    int m = m0 + wm * 64 + fm * 16 + lr;
                    int b = m >> 11, s = m & 2047, h = n >> 6, dh = n & 63;
                    out0[(((size_t)(b * 16 + h)) * 64 + dh) * 2048 + s] = f2bf(acc[fm][fn][r]);
                }
    } else {
#pragma unroll
        for (int fm = 0; fm < 4; fm++)
#pragma unroll
            for (int fn = 0; fn < 2; fn++)
#pragma unroll
                for (int r = 0; r < 4; r++) {
                    int m = m0 + wm * 64 + fm * 16 + lg * 4 + r;
                    int n = n0 + wn * 32 + fn * 16 + lr;
                    outF[(size_t)m * 1024 + n] = acc[fm][fn][r];
                }
    }
}

// ---------------- causal flash attention v9 ----------------
// v8 per-wave structure (32 q-rows = 2 sub-tiles/wave, swizzled K/V/P, 0 conflicts)
// with DEDUP'd geometry: 64-row tiles, 2-wave blocks, pairs (31-p, p) -> 33 chunks,
// grid (16,32) = 512 distinct blocks = 2 blocks/CU (barrier-decoupled).
__launch_bounds__(128, 4)
__global__ void k_attn(const short* __restrict__ Qb, const short* __restrict__ Kb,
                       const short* __restrict__ Vtb, short* __restrict__ Ob) {
    __shared__ short K_lds[2][64][64];
    __shared__ short V_lds[2][64][64];
    __shared__ short p_lds[2][2][16][64];
    int t = threadIdx.x;
    int l = t & 63, w = t >> 6;          // 2 waves
    int lr = l & 15, lg = l >> 4;

    int L = blockIdx.y * 16 + blockIdx.x;
    int bh = (L & 7) * 4 + ((L >> 3) & 3);   // XCD affinity: same bh -> same L%8
    int p = L >> 5;                          // pair index 0..15

    const short* Qp = Qb + (size_t)bh * 2048 * 64;
    const short* Kp = Kb + (size_t)bh * 2048 * 64;
    const short* Vp = Vtb + (size_t)bh * 64 * 2048;

    int n0 = 32 - p;                     // chunks for tile hi = 31-p
    int n1 = p + 1;                      // chunks for tile lo = p
    const int total = 33;

    auto stage = [&](int bb, int kv0) {
#pragma unroll
        for (int i = 0; i < 4; i++) {
            int s = t + i * 128;
            int row = s >> 3, cg = s & 7;
            int cs = (cg ^ (row & 7)) * 8;
            GLD_LDS16(&Kp[(size_t)(kv0 + row) * 64 + cs], (short*)K_lds[bb] + (size_t)s * 8);
            GLD_LDS16(&Vp[(size_t)row * 2048 + kv0 + cs], (short*)V_lds[bb] + (size_t)s * 8);
        }
    };

    stage(0, 0);

    int tile = 31 - p;
    int q0a = tile * 64 + w * 32;
    int q0b = q0a + 16;
    short8v qf0a = *(const short8v*)&Qp[(size_t)(q0a + lr) * 64 + lg * 8];
    short8v qf1a = *(const short8v*)&Qp[(size_t)(q0a + lr) * 64 + 32 + lg * 8];
    short8v qf0b = *(const short8v*)&Qp[(size_t)(q0b + lr) * 64 + lg * 8];
    short8v qf1b = *(const short8v*)&Qp[(size_t)(q0b + lr) * 64 + 32 + lg * 8];

    float4v oa[4] = {}, ob[4] = {};
    float mra[4] = {-3e38f, -3e38f, -3e38f, -3e38f};
    float mrb[4] = {-3e38f, -3e38f, -3e38f, -3e38f};
    float lsa[4] = {0.f, 0.f, 0.f, 0.f};
    float lsb[4] = {0.f, 0.f, 0.f, 0.f};
    int cur = 0;
    int b = bh >> 4, h = bh & 15;

    auto softmax_store = [&](float4v (&s)[4], float (&mr)[4], float (&ls)[4],
                             float4v (&o)[4], int X) {
        float mx[4];
#pragma unroll
        for (int r = 0; r < 4; r++)
            mx[r] = fmaxf(fmaxf(s[0][r], s[1][r]), fmaxf(s[2][r], s[3][r]));
        float worst = fmaxf(fmaxf(mx[0] - mr[0], mx[1] - mr[1]),
                            fmaxf(mx[2] - mr[2], mx[3] - mr[3]));
        if (!__all(worst <= 8.f)) {
#pragma unroll
            for (int r = 0; r < 4; r++) {
                float m_ = mx[r];
                m_ = fmaxf(m_, __shfl_xor(m_, 1));
                m_ = fmaxf(m_, __shfl_xor(m_, 2));
                m_ = fmaxf(m_, __shfl_xor(m_, 4));
                m_ = fmaxf(m_, __shfl_xor(m_, 8));
                float mnew = fmaxf(mr[r], m_);
                float sc = __builtin_amdgcn_exp2f(mr[r] - mnew);
                mr[r] = mnew;
                ls[r] *= sc;
                o[0][r] *= sc; o[1][r] *= sc; o[2][r] *= sc; o[3][r] *= sc;
            }
        }
        int bg = lr >> 3, co = lr & 7;
#pragma unroll
        for (int r = 0; r < 4; r++) {
            int row = 4 * lg + r, rx = row & 7;
            float e0 = __builtin_amdgcn_exp2f(s[0][r] - mr[r]);
            float e1 = __builtin_amdgcn_exp2f(s[1][r] - mr[r]);
            float e2 = __builtin_amdgcn_exp2f(s[2][r] - mr[r]);
            float e3 = __builtin_amdgcn_exp2f(s[3][r] - mr[r]);
            ls[r] += (e0 + e1) + (e2 + e3);
            p_lds[w][X][row][((bg    ) ^ rx) * 8 + co] = f2bf(e0);
            p_lds[w][X][row][((bg + 2) ^ rx) * 8 + co] = f2bf(e1);
            p_lds[w][X][row][((bg + 4) ^ rx) * 8 + co] = f2bf(e2);
            p_lds[w][X][row][((bg + 6) ^ rx) * 8 + co] = f2bf(e3);
        }
    };

    auto finalize = [&](float4v (&o)[4], float (&ls)[4], int q0) {
        float inv[4];
#pragma unroll
        for (int r = 0; r < 4; r++) {
            float v = ls[r];
            v += __shfl_xor(v, 1);
            v += __shfl_xor(v, 2);
            v += __shfl_xor(v, 4);
            v += __shfl_xor(v, 8);
            inv[r] = 1.0f / v;
        }
#pragma unroll
        for (int dt = 0; dt < 4; dt++)
#pragma unroll
            for (int r = 0; r < 4; r++) {
                int q = q0 + lg * 4 + r;
                Ob[((size_t)(b * 2048 + q)) * 1024 + h * 64 + dt * 16 + lr] = f2bf(o[dt][r] * inv[r]);
            }
    };

    __syncthreads();

    for (int ci = 0; ci < total; ci++) {
        bool second = ci >= n0;
        int ntile = second ? n1 : n0;
        int c = second ? ci - n0 : ci;
        int kv0 = c * 64;

        int cin = ci + 1;
        if (cin < total) {
            int kvn = (cin < n0) ? cin * 64 : (cin - n0) * 64;
            stage(cur ^ 1, kvn);
        }

        const short* Kf = (const short*)K_lds[cur];
        float4v sa[4] = {}, sb[4] = {};
        __builtin_amdgcn_s_setprio(1);
#pragma unroll
        for (int t4 = 0; t4 < 4; t4++) {
            int krow = t4 * 16 + lr;
            int sw = (krow & 7);
            short8v kfa = *(const short8v*)&Kf[krow * 64 + ((lg ^ sw) * 8)];
            short8v kfb = *(const short8v*)&Kf[krow * 64 + (((lg ^ 4) ^ sw) * 8)];
            sa[t4] = __builtin_amdgcn_mfma_f32_16x16x32_bf16(qf0a, kfa, sa[t4], 0, 0, 0);
            sa[t4] = __builtin_amdgcn_mfma_f32_16x16x32_bf16(qf1a, kfb, sa[t4], 0, 0, 0);
            sb[t4] = __builtin_amdgcn_mfma_f32_16x16x32_bf16(qf0b, kfa, sb[t4], 0, 0, 0);
            sb[t4] = __builtin_amdgcn_mfma_f32_16x16x32_bf16(qf1b, kfb, sb[t4], 0, 0, 0);
        }
        __builtin_amdgcn_s_setprio(0);

        if (kv0 + 63 > q0a) {
#pragma unroll
            for (int t4 = 0; t4 < 4; t4++)
#pragma unroll
                for (int r = 0; r < 4; r++)
                    if (kv0 + t4 * 16 + lr > q0a + lg * 4 + r) sa[t4][r] = -3e38f;
        }
        if (kv0 + 63 > q0b) {
#pragma unroll
            for (int t4 = 0; t4 < 4; t4++)
#pragma unroll
                for (int r = 0; r < 4; r++)
                    if (kv0 + t4 * 16 + lr > q0b + lg * 4 + r) sb[t4][r] = -3e38f;
        }

        softmax_store(sa, mra, lsa, oa, 0);
        softmax_store(sb, mrb, lsb, ob, 1);

        int prx = lr & 7;
        short8v pa0 = *(const short8v*)&p_lds[w][0][lr][8 * (lg ^ prx)];
        short8v pa1 = *(const short8v*)&p_lds[w][0][lr][8 * ((4 + lg) ^ prx)];
        short8v pb0 = *(const short8v*)&p_lds[w][1][lr][8 * (lg ^ prx)];
        short8v pb1 = *(const short8v*)&p_lds[w][1][lr][8 * ((4 + lg) ^ prx)];

        const short* Vf = (const short*)V_lds[cur];
        __builtin_amdgcn_s_setprio(1);
#pragma unroll
        for (int dt = 0; dt < 4; dt++) {
            int vrow = dt * 16 + lr;
            int sw = (vrow & 7);
            short8v vfa = *(const short8v*)&Vf[vrow * 64 + ((lg ^ sw) * 8)];
            short8v vfb = *(const short8v*)&Vf[vrow * 64 + (((lg ^ 4) ^ sw) * 8)];
            oa[dt] = __builtin_amdgcn_mfma_f32_16x16x32_bf16(pa0, vfa, oa[dt], 0, 0, 0);
            oa[dt] = __builtin_amdgcn_mfma_f32_16x16x32_bf16(pa1, vfb, oa[dt], 0, 0, 0);
            ob[dt] = __builtin_amdgcn_mfma_f32_16x16x32_bf16(pb0, vfa, ob[dt], 0, 0, 0);
            ob[dt] = __builtin_amdgcn_mfma_f32_16x16x32_bf16(pb1, vfb, ob[dt], 0, 0, 0);
        }
        __builtin_amdgcn_s_setprio(0);

        if (c == ntile - 1) {
            finalize(oa, lsa, q0a);
            finalize(ob, lsb, q0b);
            if (!second) {
                tile = p;
                q0a = tile * 64 + w * 32;
                q0b = q0a + 16;
                qf0a = *(const short8v*)&Qp[(size_t)(q0a + lr) * 64 + lg * 8];
                qf1a = *(const short8v*)&Qp[(size_t)(q0a + lr) * 64 + 32 + lg * 8];
                qf0b = *(const short8v*)&Qp[(size_t)(q0b + lr) * 64 + lg * 8];
                qf1b = *(const short8v*)&Qp[(size_t)(q0b + lr) * 64 + 32 + lg * 8];
#pragma unroll
                for (int dt = 0; dt < 4; dt++) {
                    oa[dt] = float4v{0.f, 0.f, 0.f, 0.f};
                    ob[dt] = float4v{0.f, 0.f, 0.f, 0.f};
                }
#pragma unroll
                for (int r = 0; r < 4; r++) {
                    mra[r] = -3e38f; mrb[r] = -3e38f;
                    lsa[r] = 0.f; lsb[r] = 0.f;
                }
            }
        }

        __syncthreads();
        cur ^= 1;
    }
}

extern "C" void kernel_launch(void* const* d_in, const int* in_sizes, int n_in,
                              void* d_out, int out_size, void* d_ws, size_t ws_size,
                              hipStream_t stream) {
    const float* x  = (const float*)d_in[0];
    const float* Wq = (const float*)d_in[1];
    const float* Wk = (const float*)d_in[2];
    const float* Wv = (const float*)d_in[3];
    const float* Wo = (const float*)d_in[4];
    float* out = (float*)d_out;

    char* ws = (char*)d_ws;
    short* xb  = (short*)(ws);                 // [4096][1024] bf16       8 MB
    short* Wtb = (short*)(ws + 8388608);       // 4 x [1024 n][1024 k]    8 MB
    short* Qb  = (short*)(ws + 16777216);      // [B,H,S,Dh] (pre-scaled) 8 MB
    short* Kb  = (short*)(ws + 25165824);      // [B,H,S,Dh]              8 MB
    short* Vtb = (short*)(ws + 33554432);      // [B,H,Dh,S]              8 MB
    short* Ob  = (short*)(ws + 41943040);      // [B,S,D] bf16            8 MB

    k_cvt_x<<<4096, 256, 0, stream>>>(x, xb);
    k_transpose<<<dim3(32, 32, 4), dim3(32, 8), 0, stream>>>(Wq, Wk, Wv, Wo, Wtb);
    k_gemm2<0><<<dim3(32, 8, 2), 512, 0, stream>>>(xb, Wtb, Qb, Kb, nullptr);
    k_gemm2<1><<<dim3(32, 8), 512, 0, stream>>>(xb, Wtb + 2 * 1048576, Vtb, nullptr, nullptr);
    k_attn<<<dim3(16, 32), 128, 0, stream>>>(Qb, Kb, Vtb, Ob);
    k_gemm2<2><<<dim3(32, 8), 512, 0, stream>>>(Ob, Wtb + 3 * 1048576, nullptr, nullptr, out);
}

// Round 11
// 121.805 us; speedup vs baseline: 1.1456x; 1.1456x over previous
//
#include <hip/hip_runtime.h>

typedef __attribute__((ext_vector_type(4))) short short4v;
typedef __attribute__((ext_vector_type(8))) short short8v;
typedef __attribute__((ext_vector_type(4))) float float4v;
typedef __attribute__((ext_vector_type(4))) int int4v;

#define GLD_LDS16(gsrc, ldst)                                                             \
    __builtin_amdgcn_global_load_lds(                                                     \
        (const __attribute__((address_space(1))) void*)(gsrc),                            \
        (__attribute__((address_space(3))) void*)(ldst), 16, 0, 0)

__device__ __forceinline__ short f2bf(float f) {
    unsigned u = __builtin_bit_cast(unsigned, f);
    u += 0x7fffu + ((u >> 16) & 1u);
    return (short)(u >> 16);
}

// ---------------- x: fp32 -> bf16 (vectorized) ----------------
__global__ void k_cvt_x(const float* __restrict__ x, short* __restrict__ xb) {
    int i = blockIdx.x * blockDim.x + threadIdx.x;
    float4v v = ((const float4v*)x)[i];
    short4v o;
    o[0] = f2bf(v[0]); o[1] = f2bf(v[1]); o[2] = f2bf(v[2]); o[3] = f2bf(v[3]);
    ((short4v*)xb)[i] = o;
}

// ---------------- W[k][n] fp32 -> Wt[n][k] bf16 (LDS tile transpose) ----------------
__global__ void k_transpose(const float* __restrict__ W0, const float* __restrict__ W1,
                            const float* __restrict__ W2, const float* __restrict__ W3,
                            short* __restrict__ Wt) {
    const float* W = blockIdx.z == 0 ? W0 : blockIdx.z == 1 ? W1 : blockIdx.z == 2 ? W2 : W3;
    short* dst = Wt + (size_t)blockIdx.z * 1024 * 1024;
    __shared__ float tile[32][33];
    int x0 = blockIdx.x * 32, y0 = blockIdx.y * 32;
    int tx = threadIdx.x, ty = threadIdx.y;
#pragma unroll
    for (int j = 0; j < 4; j++) {
        int r = ty + j * 8;
        tile[r][tx] = W[(size_t)(y0 + r) * 1024 + x0 + tx];
    }
    __syncthreads();
#pragma unroll
    for (int j = 0; j < 4; j++) {
        int r = ty + j * 8;
        dst[(size_t)(x0 + r) * 1024 + y0 + tx] = f2bf(tile[tx][r]);
    }
}

// ---------------- bf16 MFMA GEMM v2: 128x128 tile, BK=64, 8 waves, 2-phase dbuf ------
template <int MODE>
__launch_bounds__(512, 4)
__global__ void k_gemm2(const short* __restrict__ A, const short* __restrict__ Bt,
                        short* __restrict__ out0, short* __restrict__ out1,
                        float* __restrict__ outF) {
    __shared__ short As[2][128][64];
    __shared__ short Bs[2][128][64];
    int t = threadIdx.x;
    int l = t & 63, w = t >> 6;
    int wm = w >> 2, wn = w & 3;
    int lr = l & 15, lg = l >> 4;
    int m0 = blockIdx.x * 128, n0 = blockIdx.y * 128;
    const short* Bp = Bt + (MODE == 0 ? ((size_t)blockIdx.z << 20) : 0);

    int srow = l >> 3;
    int sg = (l & 7) ^ srow;
    const short* Ab0 = A + (size_t)(m0 + w * 8 + srow) * 1024 + sg * 8;
    const short* Ab1 = Ab0 + 64 * 1024;
    const short* Bb0 = Bp + (size_t)(n0 + w * 8 + srow) * 1024 + sg * 8;
    const short* Bb1 = Bb0 + 64 * 1024;

    float4v acc[4][2] = {};

#define STAGE(bb, k0)                                   \
    do {                                                \
        GLD_LDS16(Ab0 + (k0), &As[bb][w * 8][0]);       \
        GLD_LDS16(Ab1 + (k0), &As[bb][64 + w * 8][0]);  \
        GLD_LDS16(Bb0 + (k0), &Bs[bb][w * 8][0]);       \
        GLD_LDS16(Bb1 + (k0), &Bs[bb][64 + w * 8][0]);  \
    } while (0)

    STAGE(0, 0);
    __syncthreads();
    int cur = 0;

    for (int kt = 0; kt < 16; kt++) {
        if (kt + 1 < 16) STAGE(cur ^ 1, (kt + 1) * 64);
#pragma unroll
        for (int ks = 0; ks < 2; ks++) {
            short8v af[4], bfv[2];
            int hh = ks * 4 + lg;
            int sw = ((hh ^ (lr & 7)) * 8);
#pragma unroll
            for (int fm = 0; fm < 4; fm++)
                af[fm] = *(const short8v*)&As[cur][wm * 64 + fm * 16 + lr][sw];
#pragma unroll
            for (int fn = 0; fn < 2; fn++)
                bfv[fn] = *(const short8v*)&Bs[cur][wn * 32 + fn * 16 + lr][sw];
            __builtin_amdgcn_s_setprio(1);
#pragma unroll
            for (int fm = 0; fm < 4; fm++)
#pragma unroll
                for (int fn = 0; fn < 2; fn++)
                    acc[fm][fn] = (MODE == 1)
                        ? __builtin_amdgcn_mfma_f32_16x16x32_bf16(bfv[fn], af[fm], acc[fm][fn], 0, 0, 0)
                        : __builtin_amdgcn_mfma_f32_16x16x32_bf16(af[fm], bfv[fn], acc[fm][fn], 0, 0, 0);
            __builtin_amdgcn_s_setprio(0);
        }
        __syncthreads();
        cur ^= 1;
    }
#undef STAGE

    if (MODE == 0) {
        short* out = (blockIdx.z == 0) ? out0 : out1;
        float scale = (blockIdx.z == 0) ? 0.125f * 1.44269504088896f : 1.0f;
#pragma unroll
        for (int fm = 0; fm < 4; fm++)
#pragma unroll
            for (int fn = 0; fn < 2; fn++)
#pragma unroll
                for (int r = 0; r < 4; r++) {
                    int m = m0 + wm * 64 + fm * 16 + lg * 4 + r;
                    int n = n0 + wn * 32 + fn * 16 + lr;
                    float v = acc[fm][fn][r] * scale;
                    int b = m >> 11, s = m & 2047, h = n >> 6, dh = n & 63;
                    out[(((size_t)(b * 16 + h)) * 2048 + s) * 64 + dh] = f2bf(v);
                }
    } else if (MODE == 1) {
#pragma unroll
        for (int fm = 0; fm < 4; fm++)
#pragma unroll
            for (int fn = 0; fn < 2; fn++)
#pragma unroll
                for (int r = 0; r < 4; r++) {
                    int n = n0 + wn * 32 + fn * 16 + lg * 4 + r;
                    int m = m0 + wm * 64 + fm * 16 + lr;
                    int b = m >> 11, s = m & 2047, h = n >> 6, dh = n & 63;
                    out0[(((size_t)(b * 16 + h)) * 64 + dh) * 2048 + s] = f2bf(acc[fm][fn][r]);
                }
    } else {
#pragma unroll
        for (int fm = 0; fm < 4; fm++)
#pragma unroll
            for (int fn = 0; fn < 2; fn++)
#pragma unroll
                for (int r = 0; r < 4; r++) {
                    int m = m0 + wm * 64 + fm * 16 + lg * 4 + r;
                    int n = n0 + wn * 32 + fn * 16 + lr;
                    outF[(size_t)m * 1024 + n] = acc[fm][fn][r];
                }
    }
}

// ---------------- causal flash attention v10 ----------------
// v8 inner structure (4 waves x 32 q-rows, swizzled K/V/P, 0 conflicts) dedup'd:
// 512 unpaired 128-row tile blocks (32 bh x 16 tiles), all resident (2/CU,
// 8 waves/CU). Complementary blockIdx order: block i (heavy, tiles 15..8) and
// i+256 (light, tiles (i>>5)) sum to 34 chunks. bh = L&31 -> same-head = same XCD.
__launch_bounds__(256, 2)
__global__ void k_attn(const short* __restrict__ Qb, const short* __restrict__ Kb,
                       const short* __restrict__ Vtb, short* __restrict__ Ob) {
    __shared__ short K_lds[2][64][64];
    __shared__ short V_lds[2][64][64];
    __shared__ short p_lds[4][2][16][64];
    int t = threadIdx.x;
    int l = t & 63, w = t >> 6;
    int lr = l & 15, lg = l >> 4;

    int L = blockIdx.x;                      // 0..511
    int bh, tile;
    if (L < 256) { bh = L & 31; tile = 15 - (L >> 5); }          // heavy: 32..18 chunks
    else         { int j = L - 256; bh = j & 31; tile = j >> 5; } // light: 2..16 chunks
    int nch = 2 * tile + 2;

    const short* Qp = Qb + (size_t)bh * 2048 * 64;
    const short* Kp = Kb + (size_t)bh * 2048 * 64;
    const short* Vp = Vtb + (size_t)bh * 64 * 2048;

    auto stage = [&](int bb, int kv0) {
#pragma unroll
        for (int i = 0; i < 2; i++) {
            int s = t + i * 256;
            int row = s >> 3, cg = s & 7;
            int cs = (cg ^ (row & 7)) * 8;
            GLD_LDS16(&Kp[(size_t)(kv0 + row) * 64 + cs], (short*)K_lds[bb] + (size_t)s * 8);
            GLD_LDS16(&Vp[(size_t)row * 2048 + kv0 + cs], (short*)V_lds[bb] + (size_t)s * 8);
        }
    };

    stage(0, 0);

    int q0a = tile * 128 + w * 32;
    int q0b = q0a + 16;
    short8v qf0a = *(const short8v*)&Qp[(size_t)(q0a + lr) * 64 + lg * 8];
    short8v qf1a = *(const short8v*)&Qp[(size_t)(q0a + lr) * 64 + 32 + lg * 8];
    short8v qf0b = *(const short8v*)&Qp[(size_t)(q0b + lr) * 64 + lg * 8];
    short8v qf1b = *(const short8v*)&Qp[(size_t)(q0b + lr) * 64 + 32 + lg * 8];

    float4v oa[4] = {}, ob[4] = {};
    float mra[4] = {-3e38f, -3e38f, -3e38f, -3e38f};
    float mrb[4] = {-3e38f, -3e38f, -3e38f, -3e38f};
    float lsa[4] = {0.f, 0.f, 0.f, 0.f};
    float lsb[4] = {0.f, 0.f, 0.f, 0.f};
    int cur = 0;
    int b = bh >> 4, h = bh & 15;

    auto softmax_store = [&](float4v (&s)[4], float (&mr)[4], float (&ls)[4],
                             float4v (&o)[4], int X) {
        float mx[4];
#pragma unroll
        for (int r = 0; r < 4; r++)
            mx[r] = fmaxf(fmaxf(s[0][r], s[1][r]), fmaxf(s[2][r], s[3][r]));
        float worst = fmaxf(fmaxf(mx[0] - mr[0], mx[1] - mr[1]),
                            fmaxf(mx[2] - mr[2], mx[3] - mr[3]));
        if (!__all(worst <= 8.f)) {
#pragma unroll
            for (int r = 0; r < 4; r++) {
                float m_ = mx[r];
                m_ = fmaxf(m_, __shfl_xor(m_, 1));
                m_ = fmaxf(m_, __shfl_xor(m_, 2));
                m_ = fmaxf(m_, __shfl_xor(m_, 4));
                m_ = fmaxf(m_, __shfl_xor(m_, 8));
                float mnew = fmaxf(mr[r], m_);
                float sc = __builtin_amdgcn_exp2f(mr[r] - mnew);
                mr[r] = mnew;
                ls[r] *= sc;
                o[0][r] *= sc; o[1][r] *= sc; o[2][r] *= sc; o[3][r] *= sc;
            }
        }
        int bg = lr >> 3, co = lr & 7;
#pragma unroll
        for (int r = 0; r < 4; r++) {
            int row = 4 * lg + r, rx = row & 7;
            float e0 = __builtin_amdgcn_exp2f(s[0][r] - mr[r]);
            float e1 = __builtin_amdgcn_exp2f(s[1][r] - mr[r]);
            float e2 = __builtin_amdgcn_exp2f(s[2][r] - mr[r]);
            float e3 = __builtin_amdgcn_exp2f(s[3][r] - mr[r]);
            ls[r] += (e0 + e1) + (e2 + e3);
            p_lds[w][X][row][((bg    ) ^ rx) * 8 + co] = f2bf(e0);
            p_lds[w][X][row][((bg + 2) ^ rx) * 8 + co] = f2bf(e1);
            p_lds[w][X][row][((bg + 4) ^ rx) * 8 + co] = f2bf(e2);
            p_lds[w][X][row][((bg + 6) ^ rx) * 8 + co] = f2bf(e3);
        }
    };

    __syncthreads();   // prologue stage drained

    for (int ci = 0; ci < nch; ci++) {
        int kv0 = ci * 64;

        if (ci + 1 < nch) stage(cur ^ 1, (ci + 1) * 64);

        const short* Kf = (const short*)K_lds[cur];
        float4v sa[4] = {}, sb[4] = {};
        __builtin_amdgcn_s_setprio(1);
#pragma unroll
        for (int t4 = 0; t4 < 4; t4++) {
            int krow = t4 * 16 + lr;
            int sw = (krow & 7);
            short8v kfa = *(const short8v*)&Kf[krow * 64 + ((lg ^ sw) * 8)];
            short8v kfb = *(const short8v*)&Kf[krow * 64 + (((lg ^ 4) ^ sw) * 8)];
            sa[t4] = __builtin_amdgcn_mfma_f32_16x16x32_bf16(qf0a, kfa, sa[t4], 0, 0, 0);
            sa[t4] = __builtin_amdgcn_mfma_f32_16x16x32_bf16(qf1a, kfb, sa[t4], 0, 0, 0);
            sb[t4] = __builtin_amdgcn_mfma_f32_16x16x32_bf16(qf0b, kfa, sb[t4], 0, 0, 0);
            sb[t4] = __builtin_amdgcn_mfma_f32_16x16x32_bf16(qf1b, kfb, sb[t4], 0, 0, 0);
        }
        __builtin_amdgcn_s_setprio(0);

        if (kv0 + 63 > q0a) {
#pragma unroll
            for (int t4 = 0; t4 < 4; t4++)
#pragma unroll
                for (int r = 0; r < 4; r++)
                    if (kv0 + t4 * 16 + lr > q0a + lg * 4 + r) sa[t4][r] = -3e38f;
        }
        if (kv0 + 63 > q0b) {
#pragma unroll
            for (int t4 = 0; t4 < 4; t4++)
#pragma unroll
                for (int r = 0; r < 4; r++)
                    if (kv0 + t4 * 16 + lr > q0b + lg * 4 + r) sb[t4][r] = -3e38f;
        }

        softmax_store(sa, mra, lsa, oa, 0);
        softmax_store(sb, mrb, lsb, ob, 1);

        int prx = lr & 7;
        short8v pa0 = *(const short8v*)&p_lds[w][0][lr][8 * (lg ^ prx)];
        short8v pa1 = *(const short8v*)&p_lds[w][0][lr][8 * ((4 + lg) ^ prx)];
        short8v pb0 = *(const short8v*)&p_lds[w][1][lr][8 * (lg ^ prx)];
        short8v pb1 = *(const short8v*)&p_lds[w][1][lr][8 * ((4 + lg) ^ prx)];

        const short* Vf = (const short*)V_lds[cur];
        __builtin_amdgcn_s_setprio(1);
#pragma unroll
        for (int dt = 0; dt < 4; dt++) {
            int vrow = dt * 16 + lr;
            int sw = (vrow & 7);
            short8v vfa = *(const short8v*)&Vf[vrow * 64 + ((lg ^ sw) * 8)];
            short8v vfb = *(const short8v*)&Vf[vrow * 64 + (((lg ^ 4) ^ sw) * 8)];
            oa[dt] = __builtin_amdgcn_mfma_f32_16x16x32_bf16(pa0, vfa, oa[dt], 0, 0, 0);
            oa[dt] = __builtin_amdgcn_mfma_f32_16x16x32_bf16(pa1, vfb, oa[dt], 0, 0, 0);
            ob[dt] = __builtin_amdgcn_mfma_f32_16x16x32_bf16(pb0, vfa, ob[dt], 0, 0, 0);
            ob[dt] = __builtin_amdgcn_mfma_f32_16x16x32_bf16(pb1, vfb, ob[dt], 0, 0, 0);
        }
        __builtin_amdgcn_s_setprio(0);

        __syncthreads();   // buffer flip: all reads of cur done + staging drained
        cur ^= 1;
    }

    // ---- finalize both sub-tiles ----
    float inva[4], invb[4];
#pragma unroll
    for (int r = 0; r < 4; r++) {
        float va = lsa[r], vb = lsb[r];
        va += __shfl_xor(va, 1); va += __shfl_xor(va, 2);
        va += __shfl_xor(va, 4); va += __shfl_xor(va, 8);
        vb += __shfl_xor(vb, 1); vb += __shfl_xor(vb, 2);
        vb += __shfl_xor(vb, 4); vb += __shfl_xor(vb, 8);
        inva[r] = 1.0f / va;
        invb[r] = 1.0f / vb;
    }
#pragma unroll
    for (int dt = 0; dt < 4; dt++)
#pragma unroll
        for (int r = 0; r < 4; r++) {
            int qa = q0a + lg * 4 + r;
            int qb = q0b + lg * 4 + r;
            Ob[((size_t)(b * 2048 + qa)) * 1024 + h * 64 + dt * 16 + lr] = f2bf(oa[dt][r] * inva[r]);
            Ob[((size_t)(b * 2048 + qb)) * 1024 + h * 64 + dt * 16 + lr] = f2bf(ob[dt][r] * invb[r]);
        }
}

extern "C" void kernel_launch(void* const* d_in, const int* in_sizes, int n_in,
                              void* d_out, int out_size, void* d_ws, size_t ws_size,
                              hipStream_t stream) {
    const float* x  = (const float*)d_in[0];
    const float* Wq = (const float*)d_in[1];
    const float* Wk = (const float*)d_in[2];
    const float* Wv = (const float*)d_in[3];
    const float* Wo = (const float*)d_in[4];
    float* out = (float*)d_out;

    char* ws = (char*)d_ws;
    short* xb  = (short*)(ws);                 // [4096][1024] bf16       8 MB
    short* Wtb = (short*)(ws + 8388608);       // 4 x [1024 n][1024 k]    8 MB
    short* Qb  = (short*)(ws + 16777216);      // [B,H,S,Dh] (pre-scaled) 8 MB
    short* Kb  = (short*)(ws + 25165824);      // [B,H,S,Dh]              8 MB
    short* Vtb = (short*)(ws + 33554432);      // [B,H,Dh,S]              8 MB
    short* Ob  = (short*)(ws + 41943040);      // [B,S,D] bf16            8 MB

    k_cvt_x<<<4096, 256, 0, stream>>>(x, xb);
    k_transpose<<<dim3(32, 32, 4), dim3(32, 8), 0, stream>>>(Wq, Wk, Wv, Wo, Wtb);
    k_gemm2<0><<<dim3(32, 8, 2), 512, 0, stream>>>(xb, Wtb, Qb, Kb, nullptr);
    k_gemm2<1><<<dim3(32, 8), 512, 0, stream>>>(xb, Wtb + 2 * 1048576, Vtb, nullptr, nullptr);
    k_attn<<<512, 256, 0, stream>>>(Qb, Kb, Vtb, Ob);
    k_gemm2<2><<<dim3(32, 8), 512, 0, stream>>>(Ob, Wtb + 3 * 1048576, nullptr, nullptr, out);
}

// Round 12
// 118.167 us; speedup vs baseline: 1.1809x; 1.0308x over previous
//
#include <hip/hip_runtime.h>

typedef __attribute__((ext_vector_type(4))) short short4v;
typedef __attribute__((ext_vector_type(8))) short short8v;
typedef __attribute__((ext_vector_type(4))) float float4v;
typedef __attribute__((ext_vector_type(4))) int int4v;

#define GLD_LDS16(gsrc, ldst)                                                             \
    __builtin_amdgcn_global_load_lds(                                                     \
        (const __attribute__((address_space(1))) void*)(gsrc),                            \
        (__attribute__((address_space(3))) void*)(ldst), 16, 0, 0)

__device__ __forceinline__ short f2bf(float f) {
    unsigned u = __builtin_bit_cast(unsigned, f);
    u += 0x7fffu + ((u >> 16) & 1u);
    return (short)(u >> 16);
}

// ---------------- x: fp32 -> bf16 (vectorized) ----------------
__global__ void k_cvt_x(const float* __restrict__ x, short* __restrict__ xb) {
    int i = blockIdx.x * blockDim.x + threadIdx.x;
    float4v v = ((const float4v*)x)[i];
    short4v o;
    o[0] = f2bf(v[0]); o[1] = f2bf(v[1]); o[2] = f2bf(v[2]); o[3] = f2bf(v[3]);
    ((short4v*)xb)[i] = o;
}

// ---------------- W[k][n] fp32 -> Wt[n][k] bf16 (LDS tile transpose) ----------------
__global__ void k_transpose(const float* __restrict__ W0, const float* __restrict__ W1,
                            const float* __restrict__ W2, const float* __restrict__ W3,
                            short* __restrict__ Wt) {
    const float* W = blockIdx.z == 0 ? W0 : blockIdx.z == 1 ? W1 : blockIdx.z == 2 ? W2 : W3;
    short* dst = Wt + (size_t)blockIdx.z * 1024 * 1024;
    __shared__ float tile[32][33];
    int x0 = blockIdx.x * 32, y0 = blockIdx.y * 32;
    int tx = threadIdx.x, ty = threadIdx.y;
#pragma unroll
    for (int j = 0; j < 4; j++) {
        int r = ty + j * 8;
        tile[r][tx] = W[(size_t)(y0 + r) * 1024 + x0 + tx];
    }
    __syncthreads();
#pragma unroll
    for (int j = 0; j < 4; j++) {
        int r = ty + j * 8;
        dst[(size_t)(x0 + r) * 1024 + y0 + tx] = f2bf(tile[tx][r]);
    }
}

// ---------------- bf16 MFMA GEMM v2: 128x128 tile, BK=64, 8 waves, 2-phase dbuf ------
template <int MODE>
__launch_bounds__(512, 4)
__global__ void k_gemm2(const short* __restrict__ A, const short* __restrict__ Bt,
                        short* __restrict__ out0, short* __restrict__ out1,
                        float* __restrict__ outF) {
    __shared__ short As[2][128][64];
    __shared__ short Bs[2][128][64];
    int t = threadIdx.x;
    int l = t & 63, w = t >> 6;
    int wm = w >> 2, wn = w & 3;
    int lr = l & 15, lg = l >> 4;
    int m0 = blockIdx.x * 128, n0 = blockIdx.y * 128;
    const short* Bp = Bt + (MODE == 0 ? ((size_t)blockIdx.z << 20) : 0);

    int srow = l >> 3;
    int sg = (l & 7) ^ srow;
    const short* Ab0 = A + (size_t)(m0 + w * 8 + srow) * 1024 + sg * 8;
    const short* Ab1 = Ab0 + 64 * 1024;
    const short* Bb0 = Bp + (size_t)(n0 + w * 8 + srow) * 1024 + sg * 8;
    const short* Bb1 = Bb0 + 64 * 1024;

    float4v acc[4][2] = {};

#define STAGE(bb, k0)                                   \
    do {                                                \
        GLD_LDS16(Ab0 + (k0), &As[bb][w * 8][0]);       \
        GLD_LDS16(Ab1 + (k0), &As[bb][64 + w * 8][0]);  \
        GLD_LDS16(Bb0 + (k0), &Bs[bb][w * 8][0]);       \
        GLD_LDS16(Bb1 + (k0), &Bs[bb][64 + w * 8][0]);  \
    } while (0)

    STAGE(0, 0);
    __syncthreads();
    int cur = 0;

    for (int kt = 0; kt < 16; kt++) {
        if (kt + 1 < 16) STAGE(cur ^ 1, (kt + 1) * 64);
#pragma unroll
        for (int ks = 0; ks < 2; ks++) {
            short8v af[4], bfv[2];
            int hh = ks * 4 + lg;
            int sw = ((hh ^ (lr & 7)) * 8);
#pragma unroll
            for (int fm = 0; fm < 4; fm++)
                af[fm] = *(const short8v*)&As[cur][wm * 64 + fm * 16 + lr][sw];
#pragma unroll
            for (int fn = 0; fn < 2; fn++)
                bfv[fn] = *(const short8v*)&Bs[cur][wn * 32 + fn * 16 + lr][sw];
            __builtin_amdgcn_s_setprio(1);
#pragma unroll
            for (int fm = 0; fm < 4; fm++)
#pragma unroll
                for (int fn = 0; fn < 2; fn++)
                    acc[fm][fn] = (MODE == 1)
                        ? __builtin_amdgcn_mfma_f32_16x16x32_bf16(bfv[fn], af[fm], acc[fm][fn], 0, 0, 0)
                        : __builtin_amdgcn_mfma_f32_16x16x32_bf16(af[fm], bfv[fn], acc[fm][fn], 0, 0, 0);
            __builtin_amdgcn_s_setprio(0);
        }
        __syncthreads();
        cur ^= 1;
    }
#undef STAGE

    if (MODE == 0) {
        short* out = (blockIdx.z == 0) ? out0 : out1;
        float scale = (blockIdx.z == 0) ? 0.125f * 1.44269504088896f : 1.0f;
#pragma unroll
        for (int fm = 0; fm < 4; fm++)
#pragma unroll
            for (int fn = 0; fn < 2; fn++)
#pragma unroll
                for (int r = 0; r < 4; r++) {
                    int m = m0 + wm * 64 + fm * 16 + lg * 4 + r;
                    int n = n0 + wn * 32 + fn * 16 + lr;
                    float v = acc[fm][fn][r] * scale;
                    int b = m >> 11, s = m & 2047, h = n >> 6, dh = n & 63;
                    out[(((size_t)(b * 16 + h)) * 2048 + s) * 64 + dh] = f2bf(v);
                }
    } else if (MODE == 1) {
#pragma unroll
        for (int fm = 0; fm < 4; fm++)
#pragma unroll
            for (int fn = 0; fn < 2; fn++)
#pragma unroll
                for (int r = 0; r < 4; r++) {
                    int n = n0 + wn * 32 + fn * 16 + lg * 4 + r;
                    int m = m0 + wm * 64 + fm * 16 + lr;
                    int b = m >> 11, s = m & 2047, h = n >> 6, dh = n & 63;
                    out0[(((size_t)(b * 16 + h)) * 64 + dh) * 2048 + s] = f2bf(acc[fm][fn][r]);
                }
    } else {
#pragma unroll
        for (int fm = 0; fm < 4; fm++)
#pragma unroll
            for (int fn = 0; fn < 2; fn++)
#pragma unroll
                for (int r = 0; r < 4; r++) {
                    int m = m0 + wm * 64 + fm * 16 + lg * 4 + r;
                    int n = n0 + wn * 32 + fn * 16 + lr;
                    outF[(size_t)m * 1024 + n] = acc[fm][fn][r];
                }
    }
}

// ---------------- causal flash attention v11: stripe-paired tiles ----------------
// Block (bh, p): 64-row tiles hi=31-p and lo=p. Each wave owns 16 rows of hi (A)
// and 16 rows of lo (B). One staged chunk stream (nch = 32-p) serves both:
// B active while ci <= p. Per-block work near-uniform; heaviest (p=0) first.
// 512 blocks, 4 waves, 48KB LDS, 2/CU, 8 waves/CU; swizzled K/V/P, 0 conflicts.
__launch_bounds__(256, 2)
__global__ void k_attn(const short* __restrict__ Qb, const short* __restrict__ Kb,
                       const short* __restrict__ Vtb, short* __restrict__ Ob) {
    __shared__ short K_lds[2][64][64];
    __shared__ short V_lds[2][64][64];
    __shared__ short p_lds[4][2][16][64];
    int t = threadIdx.x;
    int l = t & 63, w = t >> 6;
    int lr = l & 15, lg = l >> 4;

    int L = blockIdx.x;                      // 0..511
    int bh = L & 31;                         // L%8 = bh%8 -> XCD affinity
    int p = L >> 5;                          // 0..15; p=0 heaviest, dispatched first
    int nch = 32 - p;                        // staged chunks (covers hi tile)

    const short* Qp = Qb + (size_t)bh * 2048 * 64;
    const short* Kp = Kb + (size_t)bh * 2048 * 64;
    const short* Vp = Vtb + (size_t)bh * 64 * 2048;

    auto stage = [&](int bb, int kv0) {
#pragma unroll
        for (int i = 0; i < 2; i++) {
            int s = t + i * 256;
            int row = s >> 3, cg = s & 7;
            int cs = (cg ^ (row & 7)) * 8;
            GLD_LDS16(&Kp[(size_t)(kv0 + row) * 64 + cs], (short*)K_lds[bb] + (size_t)s * 8);
            GLD_LDS16(&Vp[(size_t)row * 2048 + kv0 + cs], (short*)V_lds[bb] + (size_t)s * 8);
        }
    };

    stage(0, 0);

    int q0a = (31 - p) * 64 + w * 16;        // sub-tile A rows (hi tile)
    int q0b = p * 64 + w * 16;               // sub-tile B rows (lo tile)
    short8v qf0a = *(const short8v*)&Qp[(size_t)(q0a + lr) * 64 + lg * 8];
    short8v qf1a = *(const short8v*)&Qp[(size_t)(q0a + lr) * 64 + 32 + lg * 8];
    short8v qf0b = *(const short8v*)&Qp[(size_t)(q0b + lr) * 64 + lg * 8];
    short8v qf1b = *(const short8v*)&Qp[(size_t)(q0b + lr) * 64 + 32 + lg * 8];

    float4v oa[4] = {}, ob[4] = {};
    float mra[4] = {-3e38f, -3e38f, -3e38f, -3e38f};
    float mrb[4] = {-3e38f, -3e38f, -3e38f, -3e38f};
    float lsa[4] = {0.f, 0.f, 0.f, 0.f};
    float lsb[4] = {0.f, 0.f, 0.f, 0.f};
    int cur = 0;
    int b = bh >> 4, h = bh & 15;

    auto softmax_store = [&](float4v (&s)[4], float (&mr)[4], float (&ls)[4],
                             float4v (&o)[4], int X) {
        float mx[4];
#pragma unroll
        for (int r = 0; r < 4; r++)
            mx[r] = fmaxf(fmaxf(s[0][r], s[1][r]), fmaxf(s[2][r], s[3][r]));
        float worst = fmaxf(fmaxf(mx[0] - mr[0], mx[1] - mr[1]),
                            fmaxf(mx[2] - mr[2], mx[3] - mr[3]));
        if (!__all(worst <= 8.f)) {
#pragma unroll
            for (int r = 0; r < 4; r++) {
                float m_ = mx[r];
                m_ = fmaxf(m_, __shfl_xor(m_, 1));
                m_ = fmaxf(m_, __shfl_xor(m_, 2));
                m_ = fmaxf(m_, __shfl_xor(m_, 4));
                m_ = fmaxf(m_, __shfl_xor(m_, 8));
                float mnew = fmaxf(mr[r], m_);
                float sc = __builtin_amdgcn_exp2f(mr[r] - mnew);
                mr[r] = mnew;
                ls[r] *= sc;
                o[0][r] *= sc; o[1][r] *= sc; o[2][r] *= sc; o[3][r] *= sc;
            }
        }
        int bg = lr >> 3, co = lr & 7;
#pragma unroll
        for (int r = 0; r < 4; r++) {
            int row = 4 * lg + r, rx = row & 7;
            float e0 = __builtin_amdgcn_exp2f(s[0][r] - mr[r]);
            float e1 = __builtin_amdgcn_exp2f(s[1][r] - mr[r]);
            float e2 = __builtin_amdgcn_exp2f(s[2][r] - mr[r]);
            float e3 = __builtin_amdgcn_exp2f(s[3][r] - mr[r]);
            ls[r] += (e0 + e1) + (e2 + e3);
            p_lds[w][X][row][((bg    ) ^ rx) * 8 + co] = f2bf(e0);
            p_lds[w][X][row][((bg + 2) ^ rx) * 8 + co] = f2bf(e1);
            p_lds[w][X][row][((bg + 4) ^ rx) * 8 + co] = f2bf(e2);
            p_lds[w][X][row][((bg + 6) ^ rx) * 8 + co] = f2bf(e3);
        }
    };

    __syncthreads();   // prologue stage drained

    for (int ci = 0; ci < nch; ci++) {
        int kv0 = ci * 64;
        bool dual = (ci <= p);               // block-uniform: B sub-tile active

        if (ci + 1 < nch) stage(cur ^ 1, (ci + 1) * 64);

        const short* Kf = (const short*)K_lds[cur];
        float4v sa[4] = {}, sb[4] = {};
        __builtin_amdgcn_s_setprio(1);
#pragma unroll
        for (int t4 = 0; t4 < 4; t4++) {
            int krow = t4 * 16 + lr;
            int sw = (krow & 7);
            short8v kfa = *(const short8v*)&Kf[krow * 64 + ((lg ^ sw) * 8)];
            short8v kfb = *(const short8v*)&Kf[krow * 64 + (((lg ^ 4) ^ sw) * 8)];
            sa[t4] = __builtin_amdgcn_mfma_f32_16x16x32_bf16(qf0a, kfa, sa[t4], 0, 0, 0);
            sa[t4] = __builtin_amdgcn_mfma_f32_16x16x32_bf16(qf1a, kfb, sa[t4], 0, 0, 0);
            if (dual) {
                sb[t4] = __builtin_amdgcn_mfma_f32_16x16x32_bf16(qf0b, kfa, sb[t4], 0, 0, 0);
                sb[t4] = __builtin_amdgcn_mfma_f32_16x16x32_bf16(qf1b, kfb, sb[t4], 0, 0, 0);
            }
        }
        __builtin_amdgcn_s_setprio(0);

        if (kv0 + 63 > q0a) {                // A causal boundary (last chunk only)
#pragma unroll
            for (int t4 = 0; t4 < 4; t4++)
#pragma unroll
                for (int r = 0; r < 4; r++)
                    if (kv0 + t4 * 16 + lr > q0a + lg * 4 + r) sa[t4][r] = -3e38f;
        }
        if (dual && kv0 + 63 > q0b) {        // B causal boundary (ci == p)
#pragma unroll
            for (int t4 = 0; t4 < 4; t4++)
#pragma unroll
                for (int r = 0; r < 4; r++)
                    if (kv0 + t4 * 16 + lr > q0b + lg * 4 + r) sb[t4][r] = -3e38f;
        }

        softmax_store(sa, mra, lsa, oa, 0);
        if (dual) softmax_store(sb, mrb, lsb, ob, 1);

        int prx = lr & 7;
        short8v pa0 = *(const short8v*)&p_lds[w][0][lr][8 * (lg ^ prx)];
        short8v pa1 = *(const short8v*)&p_lds[w][0][lr][8 * ((4 + lg) ^ prx)];
        short8v pb0, pb1;
        if (dual) {
            pb0 = *(const short8v*)&p_lds[w][1][lr][8 * (lg ^ prx)];
            pb1 = *(const short8v*)&p_lds[w][1][lr][8 * ((4 + lg) ^ prx)];
        }

        const short* Vf = (const short*)V_lds[cur];
        __builtin_amdgcn_s_setprio(1);
#pragma unroll
        for (int dt = 0; dt < 4; dt++) {
            int vrow = dt * 16 + lr;
            int sw = (vrow & 7);
            short8v vfa = *(const short8v*)&Vf[vrow * 64 + ((lg ^ sw) * 8)];
            short8v vfb = *(const short8v*)&Vf[vrow * 64 + (((lg ^ 4) ^ sw) * 8)];
            oa[dt] = __builtin_amdgcn_mfma_f32_16x16x32_bf16(pa0, vfa, oa[dt], 0, 0, 0);
            oa[dt] = __builtin_amdgcn_mfma_f32_16x16x32_bf16(pa1, vfb, oa[dt], 0, 0, 0);
            if (dual) {
                ob[dt] = __builtin_amdgcn_mfma_f32_16x16x32_bf16(pb0, vfa, ob[dt], 0, 0, 0);
                ob[dt] = __builtin_amdgcn_mfma_f32_16x16x32_bf16(pb1, vfb, ob[dt], 0, 0, 0);
            }
        }
        __builtin_amdgcn_s_setprio(0);

        __syncthreads();   // buffer flip: all reads of cur done + staging drained
        cur ^= 1;
    }

    // ---- finalize both sub-tiles ----
    float inva[4], invb[4];
#pragma unroll
    for (int r = 0; r < 4; r++) {
        float va = lsa[r], vb = lsb[r];
        va += __shfl_xor(va, 1); va += __shfl_xor(va, 2);
        va += __shfl_xor(va, 4); va += __shfl_xor(va, 8);
        vb += __shfl_xor(vb, 1); vb += __shfl_xor(vb, 2);
        vb += __shfl_xor(vb, 4); vb += __shfl_xor(vb, 8);
        inva[r] = 1.0f / va;
        invb[r] = 1.0f / vb;
    }
#pragma unroll
    for (int dt = 0; dt < 4; dt++)
#pragma unroll
        for (int r = 0; r < 4; r++) {
            int qa = q0a + lg * 4 + r;
            int qb = q0b + lg * 4 + r;
            Ob[((size_t)(b * 2048 + qa)) * 1024 + h * 64 + dt * 16 + lr] = f2bf(oa[dt][r] * inva[r]);
            Ob[((size_t)(b * 2048 + qb)) * 1024 + h * 64 + dt * 16 + lr] = f2bf(ob[dt][r] * invb[r]);
        }
}

extern "C" void kernel_launch(void* const* d_in, const int* in_sizes, int n_in,
                              void* d_out, int out_size, void* d_ws, size_t ws_size,
                              hipStream_t stream) {
    const float* x  = (const float*)d_in[0];
    const float* Wq = (const float*)d_in[1];
    const float* Wk = (const float*)d_in[2];
    const float* Wv = (const float*)d_in[3];
    const float* Wo = (const float*)d_in[4];
    float* out = (float*)d_out;

    char* ws = (char*)d_ws;
    short* xb  = (short*)(ws);                 // [4096][1024] bf16       8 MB
    short* Wtb = (short*)(ws + 8388608);       // 4 x [1024 n][1024 k]    8 MB
    short* Qb  = (short*)(ws + 16777216);      // [B,H,S,Dh] (pre-scaled) 8 MB
    short* Kb  = (short*)(ws + 25165824);      // [B,H,S,Dh]              8 MB
    short* Vtb = (short*)(ws + 33554432);      // [B,H,Dh,S]              8 MB
    short* Ob  = (short*)(ws + 41943040);      // [B,S,D] bf16            8 MB

    k_cvt_x<<<4096, 256, 0, stream>>>(x, xb);
    k_transpose<<<dim3(32, 32, 4), dim3(32, 8), 0, stream>>>(Wq, Wk, Wv, Wo, Wtb);
    k_gemm2<0><<<dim3(32, 8, 2), 512, 0, stream>>>(xb, Wtb, Qb, Kb, nullptr);
    k_gemm2<1><<<dim3(32, 8), 512, 0, stream>>>(xb, Wtb + 2 * 1048576, Vtb, nullptr, nullptr);
    k_attn<<<512, 256, 0, stream>>>(Qb, Kb, Vtb, Ob);
    k_gemm2<2><<<dim3(32, 8), 512, 0, stream>>>(Ob, Wtb + 3 * 1048576, nullptr, nullptr, out);
}